// Round 1
// baseline (1228.688 us; speedup 1.0000x reference)
//
#include <hip/hip_runtime.h>
#include <cstddef>
#include <cstdint>

#define NODES 65536      // B*N
#define NEDGE 1048576    // B*E_PER
#define NB    64
#define NPER  1024
#define TOPK  512
#define BKR   32768      // NB*TOPK
#define DIM   128

// ---------------- GEMM: Out[M x 128] = A[M x 128] @ W[128 x 128] + bias ----------------
__global__ __launch_bounds__(256) void gemm128_f32(
    const float* __restrict__ A, const float* __restrict__ W,
    const float* __restrict__ bias, float* __restrict__ Out) {
  __shared__ float sW[32][128];   // k-tile of W
  __shared__ float sA[32][33];    // 32 rows x 32 k (padded)
  __shared__ float sB[128];
  const int t = threadIdx.x;
  const size_t row0 = (size_t)blockIdx.x * 32;
  const int cg = t & 31;   // cols 4*cg .. 4*cg+3
  const int rg = t >> 5;   // rows rg*4 .. rg*4+3
  if (t < 128) sB[t] = bias[t];
  float acc[4][4];
#pragma unroll
  for (int r = 0; r < 4; ++r)
#pragma unroll
    for (int c = 0; c < 4; ++c) acc[r][c] = 0.f;
  for (int kt = 0; kt < 128; kt += 32) {
    __syncthreads();
    const float4* wsrc = reinterpret_cast<const float4*>(W + (size_t)kt * 128);
    float4* wdst = reinterpret_cast<float4*>(&sW[0][0]);
#pragma unroll
    for (int i = 0; i < 4; ++i) wdst[t + i * 256] = wsrc[t + i * 256];
    {
      const int r = t >> 3;
      const int c4 = (t & 7) << 2;
      const float4 a4 = *reinterpret_cast<const float4*>(A + (row0 + r) * 128 + kt + c4);
      sA[r][c4] = a4.x; sA[r][c4 + 1] = a4.y; sA[r][c4 + 2] = a4.z; sA[r][c4 + 3] = a4.w;
    }
    __syncthreads();
#pragma unroll
    for (int kk = 0; kk < 32; ++kk) {
      const float4 w4 = *reinterpret_cast<const float4*>(&sW[kk][cg << 2]);
#pragma unroll
      for (int r = 0; r < 4; ++r) {
        const float a = sA[(rg << 2) + r][kk];
        acc[r][0] = fmaf(a, w4.x, acc[r][0]);
        acc[r][1] = fmaf(a, w4.y, acc[r][1]);
        acc[r][2] = fmaf(a, w4.z, acc[r][2]);
        acc[r][3] = fmaf(a, w4.w, acc[r][3]);
      }
    }
  }
#pragma unroll
  for (int r = 0; r < 4; ++r) {
    float4 o;
    o.x = acc[r][0] + sB[(cg << 2) + 0];
    o.y = acc[r][1] + sB[(cg << 2) + 1];
    o.z = acc[r][2] + sB[(cg << 2) + 2];
    o.w = acc[r][3] + sB[(cg << 2) + 3];
    *reinterpret_cast<float4*>(Out + (row0 + (rg << 2) + r) * 128 + (cg << 2)) = o;
  }
}

// ---------------- init ----------------
__global__ void zero_kernel(int* __restrict__ deg, float* __restrict__ bn2) {
  const int i = blockIdx.x * 256 + threadIdx.x;
  if (i < NODES) deg[i] = 0;
  if (i < 256) bn2[i] = 0.f;   // bnsum[128] + bnsq[128] contiguous
}

__global__ void pwn_kernel(const float* __restrict__ pool_w, float* __restrict__ pwn) {
  __shared__ float red[128];
  const int t = threadIdx.x;
  const float vv = pool_w[t];
  red[t] = vv * vv;
  __syncthreads();
  for (int d = 64; d > 0; d >>= 1) {
    if (t < d) red[t] += red[t + d];
    __syncthreads();
  }
  pwn[t] = vv * rsqrtf(red[0]);
}

// ---------------- CSR build ----------------
__global__ void deg_kernel(const int* __restrict__ dst, int* __restrict__ deg) {
  const int e = blockIdx.x * 256 + threadIdx.x;
  atomicAdd(&deg[dst[e]], 1);
}

__global__ __launch_bounds__(1024) void scan_kernel(const int* __restrict__ deg,
                                                    int* __restrict__ offs) {
  __shared__ int part[1024];
  const int t = threadIdx.x;
  const int base = t * 64;
  int s = 0;
  for (int j = 0; j < 64; ++j) s += deg[base + j];
  part[t] = s;
  __syncthreads();
  for (int d = 1; d < 1024; d <<= 1) {
    const int add = (t >= d) ? part[t - d] : 0;
    __syncthreads();
    part[t] += add;
    __syncthreads();
  }
  int run = part[t] - s;   // exclusive prefix of this chunk
  for (int j = 0; j < 64; ++j) { offs[base + j] = run; run += deg[base + j]; }
  if (t == 1023) offs[NODES] = run;
}

__global__ void copy_int(const int* __restrict__ a, int* __restrict__ b) {
  const int i = blockIdx.x * 256 + threadIdx.x;
  if (i < NODES) b[i] = a[i];
}

__global__ void scatter_kernel(const int* __restrict__ dst, int* __restrict__ woff,
                               int* __restrict__ eid) {
  const int e = blockIdx.x * 256 + threadIdx.x;
  const int pos = atomicAdd(&woff[dst[e]], 1);
  eid[pos] = e;
}

// ---------------- fused attention + skip + relu + score ----------------
__global__ __launch_bounds__(256) void attn_kernel(
    const float* __restrict__ q, const float* __restrict__ k,
    const float* __restrict__ v, const float* __restrict__ sk,
    const float* __restrict__ elin, const int* __restrict__ srcArr,
    const int* __restrict__ offs, const int* __restrict__ eid,
    const float* __restrict__ pwn, float* __restrict__ outc,
    float* __restrict__ score) {
  const int wid = blockIdx.x * 4 + (threadIdx.x >> 6);   // one wave per dst node
  const int lane = threadIdx.x & 63;
  const float2 qv = reinterpret_cast<const float2*>(q + (size_t)wid * DIM)[lane];
  float acc0 = 0.f, acc1 = 0.f, denom = 0.f;
  const int e0 = offs[wid], e1 = offs[wid + 1];
  for (int p = e0; p < e1; ++p) {
    const int e = eid[p];
    const int src = srcArr[e];
    const float2 kv = reinterpret_cast<const float2*>(k + (size_t)src * DIM)[lane];
    const float2 ev = reinterpret_cast<const float2*>(elin + (size_t)e * DIM)[lane];
    const float2 vv = reinterpret_cast<const float2*>(v + (size_t)src * DIM)[lane];
    float part = qv.x * (kv.x + ev.x) + qv.y * (kv.y + ev.y);
#pragma unroll
    for (int d = 32; d > 0; d >>= 1) part += __shfl_xor(part, d, 64);
    const float w = expf(part * 0.08838834764831845f);   // /sqrt(128); no max-shift needed
    denom += w;
    acc0 = fmaf(w, vv.x + ev.x, acc0);
    acc1 = fmaf(w, vv.y + ev.y, acc1);
  }
  const float inv = 1.f / (denom + 1e-16f);
  const float2 sv = reinterpret_cast<const float2*>(sk + (size_t)wid * DIM)[lane];
  const float o0 = fmaxf(fmaf(acc0, inv, sv.x), 0.f);
  const float o1 = fmaxf(fmaf(acc1, inv, sv.y), 0.f);
  reinterpret_cast<float2*>(outc + (size_t)wid * DIM)[lane] = make_float2(o0, o1);
  const float2 pw = reinterpret_cast<const float2*>(pwn)[lane];
  float sp = o0 * pw.x + o1 * pw.y;
#pragma unroll
  for (int d = 32; d > 0; d >>= 1) sp += __shfl_xor(sp, d, 64);
  if (lane == 0) score[wid] = tanhf(sp);
}

// ---------------- per-graph top-k via bitonic sort (desc, tie -> lower index) ----------------
__global__ __launch_bounds__(1024) void topk_kernel(
    const float* __restrict__ score, int* __restrict__ perm,
    float* __restrict__ tops, float* __restrict__ batchf) {
  __shared__ float ss[1024];
  __shared__ int si[1024];
  const int b = blockIdx.x, t = threadIdx.x;
  ss[t] = score[b * 1024 + t];
  si[t] = t;
  __syncthreads();
  for (int size = 2; size <= 1024; size <<= 1) {
    for (int stride = size >> 1; stride > 0; stride >>= 1) {
      const int j = t ^ stride;
      if (j > t) {
        const float s1 = ss[t], s2 = ss[j];
        const int i1 = si[t], i2 = si[j];
        const bool bj = (s2 > s1) || (s2 == s1 && i2 < i1);   // elem j should precede elem t
        const bool dir = ((t & size) == 0);
        if (dir ? bj : !bj) { ss[t] = s2; ss[j] = s1; si[t] = i2; si[j] = i1; }
      }
      __syncthreads();
    }
  }
  if (t < TOPK) {
    const int g = b * TOPK + t;
    perm[g] = b * 1024 + si[t];
    tops[g] = ss[t];
    batchf[g] = (float)b;
  }
}

__global__ void nm_init(int* __restrict__ nm) {
  const int i = blockIdx.x * 256 + threadIdx.x;
  if (i < NODES) nm[i] = -1;
}

__global__ void nm_set(const int* __restrict__ perm, int* __restrict__ nm) {
  const int i = blockIdx.x * 256 + threadIdx.x;
  if (i < BKR) nm[perm[i]] = i;
}

// ---------------- gather xp = out[perm]*top_s + BN partial sums ----------------
__global__ __launch_bounds__(128) void xp_kernel(
    const float* __restrict__ outc, const int* __restrict__ perm,
    const float* __restrict__ tops, float* __restrict__ y,
    float* __restrict__ bnsum, float* __restrict__ bnsq) {
  const int t = threadIdx.x;
  const int r0 = blockIdx.x * 128;
  float s = 0.f, s2 = 0.f;
  for (int i = 0; i < 128; ++i) {
    const int r = r0 + i;
    const int g = perm[r];
    const float val = outc[(size_t)g * DIM + t] * tops[r];
    y[(size_t)r * DIM + t] = val;
    s += val;
    s2 = fmaf(val, val, s2);
  }
  atomicAdd(&bnsum[t], s);
  atomicAdd(&bnsq[t], s2);
}

__global__ void bnfinal_kernel(const float* __restrict__ bnsum, const float* __restrict__ bnsq,
                               const float* __restrict__ gamma, const float* __restrict__ beta,
                               float* __restrict__ bnA, float* __restrict__ bnC) {
  const int t = threadIdx.x;
  const float mu = bnsum[t] * (1.f / BKR);
  const float var = bnsq[t] * (1.f / BKR) - mu * mu;
  const float inv = rsqrtf(var + 1e-5f);
  const float a = gamma[t] * inv;
  bnA[t] = a;
  bnC[t] = beta[t] - mu * a;
}

__global__ __launch_bounds__(256) void bnapply_kernel(float* __restrict__ y,
                                                      const float* __restrict__ bnA,
                                                      const float* __restrict__ bnC) {
  const size_t i4 = (size_t)blockIdx.x * 256 + threadIdx.x;   // float4 index; total BKR*32
  const int c4 = (int)(i4 & 31);
  const float4 a4 = reinterpret_cast<const float4*>(bnA)[c4];
  const float4 c4v = reinterpret_cast<const float4*>(bnC)[c4];
  float4 v = reinterpret_cast<float4*>(y)[i4];
  v.x = fmaf(v.x, a4.x, c4v.x);
  v.y = fmaf(v.y, a4.y, c4v.y);
  v.z = fmaf(v.z, a4.z, c4v.z);
  v.w = fmaf(v.w, a4.w, c4v.w);
  reinterpret_cast<float4*>(y)[i4] = v;
}

// ---------------- edge remap + valid ----------------
__global__ void efilter_kernel(const int* __restrict__ srcArr, const int* __restrict__ dstArr,
                               const int* __restrict__ nm, float* __restrict__ nei,
                               float* __restrict__ validf) {
  const int e = blockIdx.x * 256 + threadIdx.x;
  const int ns = nm[srcArr[e]];
  const int nd = nm[dstArr[e]];
  const bool val = (ns >= 0) && (nd >= 0);
  nei[e] = val ? (float)ns : -1.f;
  nei[NEDGE + e] = val ? (float)nd : -1.f;
  validf[e] = val ? 1.f : 0.f;
}

// new_edge_attr = edge_attr * valid  (overwrites the e_lin staging region)
__global__ __launch_bounds__(256) void nea_kernel(const float* __restrict__ ea,
                                                  const float* __restrict__ validf,
                                                  float* __restrict__ nea) {
  const size_t i4 = (size_t)blockIdx.x * 256 + threadIdx.x;   // total NEDGE*32 float4
  const int row = (int)(i4 >> 5);
  const float m = validf[row];
  float4 v = reinterpret_cast<const float4*>(ea)[i4];
  v.x *= m; v.y *= m; v.z *= m; v.w *= m;
  reinterpret_cast<float4*>(nea)[i4] = v;
}

// ---------------- launch ----------------
extern "C" void kernel_launch(void* const* d_in, const int* in_sizes, int n_in,
                              void* d_out, int out_size, void* d_ws, size_t ws_size,
                              hipStream_t stream) {
  const float* x     = (const float*)d_in[0];
  const int*   eidx  = (const int*)d_in[1];
  const float* eattr = (const float*)d_in[2];
  const float* Wq = (const float*)d_in[4];  const float* bq = (const float*)d_in[5];
  const float* Wk = (const float*)d_in[6];  const float* bk = (const float*)d_in[7];
  const float* Wv = (const float*)d_in[8];  const float* bv = (const float*)d_in[9];
  const float* We = (const float*)d_in[10]; const float* be = (const float*)d_in[11];
  const float* Ws = (const float*)d_in[12]; const float* bs = (const float*)d_in[13];
  const float* pool_w = (const float*)d_in[14];
  const float* gamma  = (const float*)d_in[15];
  const float* beta   = (const float*)d_in[16];

  const int* srcArr = eidx;
  const int* dstArr = eidx + NEDGE;

  float* out = (float*)d_out;
  // output layout (floats)
  float* y      = out;                                   // 32768*128
  float* nei    = out + (size_t)BKR * DIM;               // 2*NEDGE
  float* nea    = nei + 2 * (size_t)NEDGE;               // NEDGE*128 (staging for e_lin first)
  float* batchf = nea + (size_t)NEDGE * DIM;             // BKR
  float* validf = batchf + BKR;                          // NEDGE
  float* elin   = nea;                                   // staged in nea region

  // workspace layout
  char* w = (char*)d_ws;
  size_t off = 0;
  float* q    = (float*)(w + off); off += (size_t)NODES * DIM * 4;
  float* kl   = (float*)(w + off); off += (size_t)NODES * DIM * 4;
  float* vl   = (float*)(w + off); off += (size_t)NODES * DIM * 4;
  float* sl   = (float*)(w + off); off += (size_t)NODES * DIM * 4;
  float* outc = (float*)(w + off); off += (size_t)NODES * DIM * 4;
  float* score= (float*)(w + off); off += (size_t)NODES * 4;
  float* pwn  = (float*)(w + off); off += 128 * 4;
  float* tops = (float*)(w + off); off += (size_t)BKR * 4;
  float* bnsum= (float*)(w + off); off += 128 * 4;
  float* bnsq = (float*)(w + off); off += 128 * 4;
  float* bnA  = (float*)(w + off); off += 128 * 4;
  float* bnC  = (float*)(w + off); off += 128 * 4;
  int* deg    = (int*)(w + off); off += (size_t)NODES * 4;
  int* offs   = (int*)(w + off); off += ((size_t)NODES + 1) * 4;
  int* woff   = (int*)(w + off); off += (size_t)NODES * 4;
  int* nmap   = (int*)(w + off); off += (size_t)NODES * 4;
  int* perm   = (int*)(w + off); off += (size_t)BKR * 4;
  int* eid    = (int*)(w + off); off += (size_t)NEDGE * 4;

  // init
  zero_kernel<<<NODES / 256, 256, 0, stream>>>(deg, bnsum);   // bnsum+bnsq contiguous
  pwn_kernel<<<1, 128, 0, stream>>>(pool_w, pwn);

  // linear layers
  gemm128_f32<<<NODES / 32, 256, 0, stream>>>(x, Wq, bq, q);
  gemm128_f32<<<NODES / 32, 256, 0, stream>>>(x, Wk, bk, kl);
  gemm128_f32<<<NODES / 32, 256, 0, stream>>>(x, Wv, bv, vl);
  gemm128_f32<<<NODES / 32, 256, 0, stream>>>(x, Ws, bs, sl);
  gemm128_f32<<<NEDGE / 32, 256, 0, stream>>>(eattr, We, be, elin);

  // CSR by dst
  deg_kernel<<<NEDGE / 256, 256, 0, stream>>>(dstArr, deg);
  scan_kernel<<<1, 1024, 0, stream>>>(deg, offs);
  copy_int<<<NODES / 256, 256, 0, stream>>>(offs, woff);
  scatter_kernel<<<NEDGE / 256, 256, 0, stream>>>(dstArr, woff, eid);

  // fused attention
  attn_kernel<<<NODES / 4, 256, 0, stream>>>(q, kl, vl, sl, elin, srcArr, offs, eid,
                                             pwn, outc, score);

  // top-k pooling
  topk_kernel<<<NB, 1024, 0, stream>>>(score, perm, tops, batchf);
  nm_init<<<NODES / 256, 256, 0, stream>>>(nmap);
  nm_set<<<BKR / 256, 256, 0, stream>>>(perm, nmap);

  // xp gather + BN
  xp_kernel<<<BKR / 128, 128, 0, stream>>>(outc, perm, tops, y, bnsum, bnsq);
  bnfinal_kernel<<<1, 128, 0, stream>>>(bnsum, bnsq, gamma, beta, bnA, bnC);
  bnapply_kernel<<<(BKR * 32) / 256, 256, 0, stream>>>(y, bnA, bnC);

  // edge remap + masked edge_attr (overwrites e_lin staging)
  efilter_kernel<<<NEDGE / 256, 256, 0, stream>>>(srcArr, dstArr, nmap, nei, validf);
  nea_kernel<<<(NEDGE * 32) / 256, 256, 0, stream>>>(eattr, validf, nea);
}

// Round 3
// 906.919 us; speedup vs baseline: 1.3548x; 1.3548x over previous
//
#include <hip/hip_runtime.h>
#include <cstddef>
#include <cstdint>

#define NODES 65536      // B*N
#define NEDGE 1048576    // B*E_PER
#define NB    64
#define NPER  1024
#define TOPK  512
#define BKR   32768      // NB*TOPK
#define DIM   128
#define NM    ((size_t)NODES * DIM)   // floats per node-array

__device__ __forceinline__ void fma4(float4& acc, float av, const float4& wv) {
  acc.x = fmaf(av, wv.x, acc.x);
  acc.y = fmaf(av, wv.y, acc.y);
  acc.z = fmaf(av, wv.z, acc.z);
  acc.w = fmaf(av, wv.w, acc.w);
}

// ================= GEMM v2: Out[Mx128] = A[Mx128] @ W[128x128] + bias =================
// 256 threads, 128-row tile, 8x8 per-thread blocking, W resident in LDS (64KB),
// A read directly from global. No syncthreads in main loop.
__global__ __launch_bounds__(256) void gemm_v2(
    const float* __restrict__ A, const float* __restrict__ W,
    const float* __restrict__ bias, float* __restrict__ Out) {
  __shared__ float4 sW[128 * 32];
  const int t = threadIdx.x;
  const float4* W4 = reinterpret_cast<const float4*>(W);
#pragma unroll
  for (int i = 0; i < 16; ++i) sW[t + i * 256] = W4[t + i * 256];
  const int tc = t & 15;          // col group: cols tc*8 .. tc*8+7
  const int tr = t >> 4;          // row group: rows tr*8 .. tr*8+7
  const size_t row0 = (size_t)blockIdx.x * 128 + tr * 8;
  const float* a0 = A + row0 * 128;
  float4 acc0[8], acc1[8];
#pragma unroll
  for (int r = 0; r < 8; ++r) {
    acc0[r] = make_float4(0.f, 0.f, 0.f, 0.f);
    acc1[r] = make_float4(0.f, 0.f, 0.f, 0.f);
  }
  __syncthreads();
#pragma unroll 4
  for (int k4 = 0; k4 < 32; ++k4) {
    float4 a[8];
#pragma unroll
    for (int r = 0; r < 8; ++r)
      a[r] = *reinterpret_cast<const float4*>(a0 + r * 128 + k4 * 4);
#pragma unroll
    for (int kk = 0; kk < 4; ++kk) {
      const float4 w0 = sW[(k4 * 4 + kk) * 32 + tc * 2];
      const float4 w1 = sW[(k4 * 4 + kk) * 32 + tc * 2 + 1];
#pragma unroll
      for (int r = 0; r < 8; ++r) {
        const float av = reinterpret_cast<const float*>(&a[r])[kk];
        fma4(acc0[r], av, w0);
        fma4(acc1[r], av, w1);
      }
    }
  }
  const float4 b0 = reinterpret_cast<const float4*>(bias)[tc * 2];
  const float4 b1 = reinterpret_cast<const float4*>(bias)[tc * 2 + 1];
#pragma unroll
  for (int r = 0; r < 8; ++r) {
    float4 o0 = acc0[r], o1 = acc1[r];
    o0.x += b0.x; o0.y += b0.y; o0.z += b0.z; o0.w += b0.w;
    o1.x += b1.x; o1.y += b1.y; o1.z += b1.z; o1.w += b1.w;
    float4* outp = reinterpret_cast<float4*>(Out + (row0 + r) * 128 + tc * 8);
    outp[0] = o0; outp[1] = o1;
  }
}

// ====== final GEMM: out = relu(agge@We + be + aggv + sl); outc + score epilogue ======
__global__ __launch_bounds__(256) void gemm_final(
    const float* __restrict__ A, const float* __restrict__ W,
    const float* __restrict__ bias, const float* __restrict__ aggv,
    const float* __restrict__ sl, const float* __restrict__ pwn,
    float* __restrict__ outc, float* __restrict__ score) {
  __shared__ float4 sW[128 * 32];
  const int t = threadIdx.x;
  const float4* W4 = reinterpret_cast<const float4*>(W);
#pragma unroll
  for (int i = 0; i < 16; ++i) sW[t + i * 256] = W4[t + i * 256];
  const int tc = t & 15;
  const int tr = t >> 4;
  const size_t row0 = (size_t)blockIdx.x * 128 + tr * 8;
  const float* a0 = A + row0 * 128;
  float4 acc0[8], acc1[8];
#pragma unroll
  for (int r = 0; r < 8; ++r) {
    acc0[r] = make_float4(0.f, 0.f, 0.f, 0.f);
    acc1[r] = make_float4(0.f, 0.f, 0.f, 0.f);
  }
  __syncthreads();
#pragma unroll 4
  for (int k4 = 0; k4 < 32; ++k4) {
    float4 a[8];
#pragma unroll
    for (int r = 0; r < 8; ++r)
      a[r] = *reinterpret_cast<const float4*>(a0 + r * 128 + k4 * 4);
#pragma unroll
    for (int kk = 0; kk < 4; ++kk) {
      const float4 w0 = sW[(k4 * 4 + kk) * 32 + tc * 2];
      const float4 w1 = sW[(k4 * 4 + kk) * 32 + tc * 2 + 1];
#pragma unroll
      for (int r = 0; r < 8; ++r) {
        const float av = reinterpret_cast<const float*>(&a[r])[kk];
        fma4(acc0[r], av, w0);
        fma4(acc1[r], av, w1);
      }
    }
  }
  const float4 b0 = reinterpret_cast<const float4*>(bias)[tc * 2];
  const float4 b1 = reinterpret_cast<const float4*>(bias)[tc * 2 + 1];
  const float4 p0 = reinterpret_cast<const float4*>(pwn)[tc * 2];
  const float4 p1 = reinterpret_cast<const float4*>(pwn)[tc * 2 + 1];
#pragma unroll
  for (int r = 0; r < 8; ++r) {
    const float4 v0 = reinterpret_cast<const float4*>(aggv + (row0 + r) * 128 + tc * 8)[0];
    const float4 v1 = reinterpret_cast<const float4*>(aggv + (row0 + r) * 128 + tc * 8)[1];
    const float4 s0 = reinterpret_cast<const float4*>(sl + (row0 + r) * 128 + tc * 8)[0];
    const float4 s1 = reinterpret_cast<const float4*>(sl + (row0 + r) * 128 + tc * 8)[1];
    float4 o0, o1;
    o0.x = fmaxf(acc0[r].x + b0.x + v0.x + s0.x, 0.f);
    o0.y = fmaxf(acc0[r].y + b0.y + v0.y + s0.y, 0.f);
    o0.z = fmaxf(acc0[r].z + b0.z + v0.z + s0.z, 0.f);
    o0.w = fmaxf(acc0[r].w + b0.w + v0.w + s0.w, 0.f);
    o1.x = fmaxf(acc1[r].x + b1.x + v1.x + s1.x, 0.f);
    o1.y = fmaxf(acc1[r].y + b1.y + v1.y + s1.y, 0.f);
    o1.z = fmaxf(acc1[r].z + b1.z + v1.z + s1.z, 0.f);
    o1.w = fmaxf(acc1[r].w + b1.w + v1.w + s1.w, 0.f);
    float4* outp = reinterpret_cast<float4*>(outc + (row0 + r) * 128 + tc * 8);
    outp[0] = o0; outp[1] = o1;
    float sp = o0.x * p0.x + o0.y * p0.y + o0.z * p0.z + o0.w * p0.w +
               o1.x * p1.x + o1.y * p1.y + o1.z * p1.z + o1.w * p1.w;
#pragma unroll
    for (int d = 1; d < 16; d <<= 1) sp += __shfl_xor(sp, d, 16);
    if (tc == 0) score[row0 + r] = tanhf(sp);
  }
}

// ============ Wc[t,i] = sum_d Wq[t,d]*We[i,d];  bc[i] = sum_d bq[d]*We[i,d] ============
__global__ void wc_kernel(const float* __restrict__ Wq, const float* __restrict__ bq,
                          const float* __restrict__ We, float* __restrict__ Wc,
                          float* __restrict__ bc) {
  __shared__ float sWe[128];
  const int i = blockIdx.x;    // output col (in-index of We row)
  const int t = threadIdx.x;   // 128 threads = output row
  sWe[t] = We[i * 128 + t];
  __syncthreads();
  float s = 0.f;
  for (int d = 0; d < 128; ++d) s = fmaf(Wq[t * 128 + d], sWe[d], s);
  Wc[t * 128 + i] = s;
  if (t == 0) {
    float sb = 0.f;
    for (int d = 0; d < 128; ++d) sb = fmaf(bq[d], sWe[d], sb);
    bc[i] = sb;
  }
}

// ---------------- init ----------------
__global__ void init_kernel(int* __restrict__ deg, int* __restrict__ nmap,
                            float* __restrict__ bn2) {
  const int i = blockIdx.x * 256 + threadIdx.x;
  if (i < NODES) { deg[i] = 0; nmap[i] = -1; }
  if (i < 256) bn2[i] = 0.f;   // bnsum[128] + bnsq[128] contiguous
}

__global__ void pwn_kernel(const float* __restrict__ pool_w, float* __restrict__ pwn) {
  __shared__ float red[128];
  const int t = threadIdx.x;
  const float vv = pool_w[t];
  red[t] = vv * vv;
  __syncthreads();
  for (int d = 64; d > 0; d >>= 1) {
    if (t < d) red[t] += red[t + d];
    __syncthreads();
  }
  pwn[t] = vv * rsqrtf(red[0]);
}

// ---------------- CSR build ----------------
__global__ void deg_kernel(const int* __restrict__ dst, int* __restrict__ deg) {
  const int e = blockIdx.x * 256 + threadIdx.x;
  atomicAdd(&deg[dst[e]], 1);
}

__global__ __launch_bounds__(1024) void scan_kernel(const int* __restrict__ deg,
                                                    int* __restrict__ offs) {
  __shared__ int part[1024];
  const int t = threadIdx.x;
  const int base = t * 64;
  int s = 0;
  for (int j = 0; j < 64; ++j) s += deg[base + j];
  part[t] = s;
  __syncthreads();
  for (int d = 1; d < 1024; d <<= 1) {
    const int add = (t >= d) ? part[t - d] : 0;
    __syncthreads();
    part[t] += add;
    __syncthreads();
  }
  int run = part[t] - s;
  for (int j = 0; j < 64; ++j) { offs[base + j] = run; run += deg[base + j]; }
  if (t == 1023) offs[NODES] = run;
}

__global__ void copy_int(const int* __restrict__ a, int* __restrict__ b) {
  const int i = blockIdx.x * 256 + threadIdx.x;
  if (i < NODES) b[i] = a[i];
}

__global__ void scatter_kernel(const int* __restrict__ dst, int* __restrict__ woff,
                               int* __restrict__ eid) {
  const int e = blockIdx.x * 256 + threadIdx.x;
  const int pos = atomicAdd(&woff[dst[e]], 1);
  eid[pos] = e;
}

// ========== fused attention on RAW edge_attr; writes aggv, agge (normalized) ==========
__global__ __launch_bounds__(256) void attn_v2(
    const float* __restrict__ q, const float* __restrict__ k,
    const float* __restrict__ v, const float* __restrict__ qw,
    const float* __restrict__ ea, const float* __restrict__ be,
    const int* __restrict__ srcArr, const int* __restrict__ offs,
    const int* __restrict__ eid, float* __restrict__ aggv,
    float* __restrict__ agge) {
  int b = blockIdx.x;
  b = (b & 7) * 2048 + (b >> 3);                        // XCD-bijective swizzle (16384%8==0)
  const int wid = b * 4 + (threadIdx.x >> 6);
  const int lane = threadIdx.x & 63;
  const float2 qv  = reinterpret_cast<const float2*>(q  + (size_t)wid * DIM)[lane];
  const float2 qwv = reinterpret_cast<const float2*>(qw + (size_t)wid * DIM)[lane];
  const float2 bev = reinterpret_cast<const float2*>(be)[lane];
  float qbe = qv.x * bev.x + qv.y * bev.y;
#pragma unroll
  for (int d = 32; d > 0; d >>= 1) qbe += __shfl_xor(qbe, d, 64);
  float denom = 0.f, av0 = 0.f, av1 = 0.f, ae0 = 0.f, ae1 = 0.f;
  const int e0 = offs[wid], e1 = offs[wid + 1];
  for (int p = e0; p < e1; ++p) {
    const int e = eid[p];
    const int src = srcArr[e];
    const float2 kv  = reinterpret_cast<const float2*>(k + (size_t)src * DIM)[lane];
    const float2 eav = reinterpret_cast<const float2*>(ea + (size_t)e * DIM)[lane];
    const float2 vv  = reinterpret_cast<const float2*>(v + (size_t)src * DIM)[lane];
    float part = qv.x * kv.x + qv.y * kv.y + qwv.x * eav.x + qwv.y * eav.y;
#pragma unroll
    for (int d = 32; d > 0; d >>= 1) part += __shfl_xor(part, d, 64);
    const float wgt = expf((part + qbe) * 0.08838834764831845f);   // /sqrt(128)
    denom += wgt;
    av0 = fmaf(wgt, vv.x, av0);  av1 = fmaf(wgt, vv.y, av1);
    ae0 = fmaf(wgt, eav.x, ae0); ae1 = fmaf(wgt, eav.y, ae1);
  }
  const float inv = 1.f / (denom + 1e-16f);
  reinterpret_cast<float2*>(aggv + (size_t)wid * DIM)[lane] = make_float2(av0 * inv, av1 * inv);
  reinterpret_cast<float2*>(agge + (size_t)wid * DIM)[lane] = make_float2(ae0 * inv, ae1 * inv);
}

// -------- per-graph top-k via bitonic sort (desc, tie -> lower index) --------
__global__ __launch_bounds__(1024) void topk_kernel(
    const float* __restrict__ score, int* __restrict__ perm,
    float* __restrict__ tops, float* __restrict__ batchf) {
  __shared__ float ss[1024];
  __shared__ int si[1024];
  const int b = blockIdx.x, t = threadIdx.x;
  ss[t] = score[b * 1024 + t];
  si[t] = t;
  __syncthreads();
  for (int size = 2; size <= 1024; size <<= 1) {
    for (int stride = size >> 1; stride > 0; stride >>= 1) {
      const int j = t ^ stride;
      if (j > t) {
        const float s1 = ss[t], s2 = ss[j];
        const int i1 = si[t], i2 = si[j];
        const bool bj = (s2 > s1) || (s2 == s1 && i2 < i1);
        const bool dir = ((t & size) == 0);
        if (dir ? bj : !bj) { ss[t] = s2; ss[j] = s1; si[t] = i2; si[j] = i1; }
      }
      __syncthreads();
    }
  }
  if (t < TOPK) {
    const int g = b * TOPK + t;
    perm[g] = b * 1024 + si[t];
    tops[g] = ss[t];
    batchf[g] = (float)b;
  }
}

__global__ void nm_set(const int* __restrict__ perm, int* __restrict__ nm) {
  const int i = blockIdx.x * 256 + threadIdx.x;
  if (i < BKR) nm[perm[i]] = i;
}

// ------------- gather xp = out[perm]*top_s + BN partial sums -------------
__global__ __launch_bounds__(128) void xp_kernel(
    const float* __restrict__ outc, const int* __restrict__ perm,
    const float* __restrict__ tops, float* __restrict__ y,
    float* __restrict__ bnsum, float* __restrict__ bnsq) {
  const int t = threadIdx.x;
  const int r0 = blockIdx.x * 128;
  float s = 0.f, s2 = 0.f;
  for (int i = 0; i < 128; ++i) {
    const int r = r0 + i;
    const int g = perm[r];
    const float val = outc[(size_t)g * DIM + t] * tops[r];
    y[(size_t)r * DIM + t] = val;
    s += val;
    s2 = fmaf(val, val, s2);
  }
  atomicAdd(&bnsum[t], s);
  atomicAdd(&bnsq[t], s2);
}

__global__ void bnfinal_kernel(const float* __restrict__ bnsum, const float* __restrict__ bnsq,
                               const float* __restrict__ gamma, const float* __restrict__ beta,
                               float* __restrict__ bnA, float* __restrict__ bnC) {
  const int t = threadIdx.x;
  const float mu = bnsum[t] * (1.f / BKR);
  const float var = bnsq[t] * (1.f / BKR) - mu * mu;
  const float inv = rsqrtf(var + 1e-5f);
  const float a = gamma[t] * inv;
  bnA[t] = a;
  bnC[t] = beta[t] - mu * a;
}

__global__ __launch_bounds__(256) void bnapply_kernel(float* __restrict__ y,
                                                      const float* __restrict__ bnA,
                                                      const float* __restrict__ bnC) {
  const size_t i4 = (size_t)blockIdx.x * 256 + threadIdx.x;   // BKR*32 float4s
  const int c4 = (int)(i4 & 31);
  const float4 a4 = reinterpret_cast<const float4*>(bnA)[c4];
  const float4 c4v = reinterpret_cast<const float4*>(bnC)[c4];
  float4 v = reinterpret_cast<float4*>(y)[i4];
  v.x = fmaf(v.x, a4.x, c4v.x);
  v.y = fmaf(v.y, a4.y, c4v.y);
  v.z = fmaf(v.z, a4.z, c4v.z);
  v.w = fmaf(v.w, a4.w, c4v.w);
  reinterpret_cast<float4*>(y)[i4] = v;
}

// ---------------- edge remap + valid ----------------
__global__ void efilter_kernel(const int* __restrict__ srcArr, const int* __restrict__ dstArr,
                               const int* __restrict__ nm, float* __restrict__ nei,
                               float* __restrict__ validf) {
  const int e = blockIdx.x * 256 + threadIdx.x;
  const int ns = nm[srcArr[e]];
  const int nd = nm[dstArr[e]];
  const bool val = (ns >= 0) && (nd >= 0);
  nei[e] = val ? (float)ns : -1.f;
  nei[NEDGE + e] = val ? (float)nd : -1.f;
  validf[e] = val ? 1.f : 0.f;
}

// new_edge_attr: skip reading invalid rows (write zeros), 8 rows per 256-thread block
__global__ __launch_bounds__(256) void nea_kernel(const float* __restrict__ ea,
                                                  const float* __restrict__ validf,
                                                  float* __restrict__ nea) {
  const int t = threadIdx.x;
  const int row = blockIdx.x * 8 + (t >> 5);
  const int lane = t & 31;
  const size_t i4 = (size_t)row * 32 + lane;
  float4 v = make_float4(0.f, 0.f, 0.f, 0.f);
  if (validf[row] > 0.5f) v = reinterpret_cast<const float4*>(ea)[i4];
  reinterpret_cast<float4*>(nea)[i4] = v;
}

// ---------------- launch ----------------
extern "C" void kernel_launch(void* const* d_in, const int* in_sizes, int n_in,
                              void* d_out, int out_size, void* d_ws, size_t ws_size,
                              hipStream_t stream) {
  const float* x     = (const float*)d_in[0];
  const int*   eidx  = (const int*)d_in[1];
  const float* eattr = (const float*)d_in[2];
  const float* Wq = (const float*)d_in[4];  const float* bq = (const float*)d_in[5];
  const float* Wk = (const float*)d_in[6];  const float* bk = (const float*)d_in[7];
  const float* Wv = (const float*)d_in[8];  const float* bv = (const float*)d_in[9];
  const float* We = (const float*)d_in[10]; const float* be = (const float*)d_in[11];
  const float* Ws = (const float*)d_in[12]; const float* bs = (const float*)d_in[13];
  const float* pool_w = (const float*)d_in[14];
  const float* gamma  = (const float*)d_in[15];
  const float* beta   = (const float*)d_in[16];

  const int* srcArr = eidx;
  const int* dstArr = eidx + NEDGE;

  float* out = (float*)d_out;
  // output layout (floats)
  float* y      = out;                                   // BKR*128
  float* nei    = out + (size_t)BKR * DIM;               // 2*NEDGE
  float* nea    = nei + 2 * (size_t)NEDGE;               // NEDGE*128
  float* batchf = nea + (size_t)NEDGE * DIM;             // BKR
  float* validf = batchf + BKR;                          // NEDGE

  // big node arrays staged inside the (not-yet-written) nea region: 8 x 32MB = 256MB
  float* q    = nea + 0 * NM;
  float* kl   = nea + 1 * NM;
  float* vl   = nea + 2 * NM;
  float* sl   = nea + 3 * NM;
  float* qw   = nea + 4 * NM;
  float* aggv = nea + 5 * NM;
  float* agge = nea + 6 * NM;
  float* outc = nea + 7 * NM;

  // workspace layout (small)
  char* w = (char*)d_ws;
  size_t off = 0;
  float* score= (float*)(w + off); off += (size_t)NODES * 4;
  float* pwn  = (float*)(w + off); off += 128 * 4;
  float* Wc   = (float*)(w + off); off += 128 * 128 * 4;
  float* bc   = (float*)(w + off); off += 128 * 4;
  float* tops = (float*)(w + off); off += (size_t)BKR * 4;
  float* bnsum= (float*)(w + off); off += 128 * 4;
  float* bnsq = (float*)(w + off); off += 128 * 4;
  float* bnA  = (float*)(w + off); off += 128 * 4;
  float* bnC  = (float*)(w + off); off += 128 * 4;
  int* deg    = (int*)(w + off); off += (size_t)NODES * 4;
  int* offs   = (int*)(w + off); off += ((size_t)NODES + 1) * 4;
  int* woff   = (int*)(w + off); off += (size_t)NODES * 4;
  int* nmap   = (int*)(w + off); off += (size_t)NODES * 4;
  int* perm   = (int*)(w + off); off += (size_t)BKR * 4;
  int* eid    = (int*)(w + off); off += (size_t)NEDGE * 4;

  // init + tiny precomputes
  init_kernel<<<NODES / 256, 256, 0, stream>>>(deg, nmap, bnsum);
  pwn_kernel<<<1, 128, 0, stream>>>(pool_w, pwn);
  wc_kernel<<<128, 128, 0, stream>>>(Wq, bq, We, Wc, bc);

  // node-level linear layers (q, k, v, skip, qW)
  gemm_v2<<<NODES / 128, 256, 0, stream>>>(x, Wq, bq, q);
  gemm_v2<<<NODES / 128, 256, 0, stream>>>(x, Wk, bk, kl);
  gemm_v2<<<NODES / 128, 256, 0, stream>>>(x, Wv, bv, vl);
  gemm_v2<<<NODES / 128, 256, 0, stream>>>(x, Ws, bs, sl);
  gemm_v2<<<NODES / 128, 256, 0, stream>>>(x, Wc, bc, qw);

  // CSR by dst
  deg_kernel<<<NEDGE / 256, 256, 0, stream>>>(dstArr, deg);
  scan_kernel<<<1, 1024, 0, stream>>>(deg, offs);
  copy_int<<<NODES / 256, 256, 0, stream>>>(offs, woff);
  scatter_kernel<<<NEDGE / 256, 256, 0, stream>>>(dstArr, woff, eid);

  // fused attention on raw edge_attr
  attn_v2<<<NODES / 4, 256, 0, stream>>>(q, kl, vl, qw, eattr, be, srcArr, offs, eid,
                                         aggv, agge);

  // final conv output + score
  gemm_final<<<NODES / 128, 256, 0, stream>>>(agge, We, be, aggv, sl, pwn, outc, score);

  // top-k pooling
  topk_kernel<<<NB, 1024, 0, stream>>>(score, perm, tops, batchf);
  nm_set<<<BKR / 256, 256, 0, stream>>>(perm, nmap);

  // xp gather + BN (must finish with outc before nea overwrite)
  xp_kernel<<<BKR / 128, 128, 0, stream>>>(outc, perm, tops, y, bnsum, bnsq);
  bnfinal_kernel<<<1, 128, 0, stream>>>(bnsum, bnsq, gamma, beta, bnA, bnC);
  bnapply_kernel<<<(BKR * 32) / 256, 256, 0, stream>>>(y, bnA, bnC);

  // edge remap + masked edge_attr (overwrites staging region last)
  efilter_kernel<<<NEDGE / 256, 256, 0, stream>>>(srcArr, dstArr, nmap, nei, validf);
  nea_kernel<<<NEDGE / 8, 256, 0, stream>>>(eattr, validf, nea);
}

// Round 4
// 815.106 us; speedup vs baseline: 1.5074x; 1.1126x over previous
//
#include <hip/hip_runtime.h>
#include <cstddef>
#include <cstdint>

#define NODES 65536      // B*N
#define NEDGE 1048576    // B*E_PER
#define NB    64
#define NPER  1024
#define TOPK  512
#define BKR   32768      // NB*TOPK
#define DIM   128
#define NM    ((size_t)NODES * DIM)   // floats per node-array

__device__ __forceinline__ void fma4(float4& acc, float av, const float4& wv) {
  acc.x = fmaf(av, wv.x, acc.x);
  acc.y = fmaf(av, wv.y, acc.y);
  acc.z = fmaf(av, wv.z, acc.z);
  acc.w = fmaf(av, wv.w, acc.w);
}

__device__ __forceinline__ float dot4(const float4& a, const float4& b) {
  return fmaf(a.x, b.x, fmaf(a.y, b.y, fmaf(a.z, b.z, a.w * b.w)));
}

// ================= GEMM: Out[Mx128] = A[Mx128] @ W[128x128] + bias =================
// 256 threads, 128-row tile, 8x8 per-thread blocking, W resident in LDS (64KB).
__device__ __forceinline__ void gemm_body(
    const float* __restrict__ A, const float* __restrict__ W,
    const float* __restrict__ bias, float* __restrict__ Out, int bid) {
  __shared__ float4 sW[128 * 32];
  const int t = threadIdx.x;
  const float4* W4 = reinterpret_cast<const float4*>(W);
#pragma unroll
  for (int i = 0; i < 16; ++i) sW[t + i * 256] = W4[t + i * 256];
  const int tc = t & 15;          // col group: cols tc*8 .. tc*8+7
  const int tr = t >> 4;          // row group: rows tr*8 .. tr*8+7
  const size_t row0 = (size_t)bid * 128 + tr * 8;
  const float* a0 = A + row0 * 128;
  float4 acc0[8], acc1[8];
#pragma unroll
  for (int r = 0; r < 8; ++r) {
    acc0[r] = make_float4(0.f, 0.f, 0.f, 0.f);
    acc1[r] = make_float4(0.f, 0.f, 0.f, 0.f);
  }
  __syncthreads();
#pragma unroll 4
  for (int k4 = 0; k4 < 32; ++k4) {
    float4 a[8];
#pragma unroll
    for (int r = 0; r < 8; ++r)
      a[r] = *reinterpret_cast<const float4*>(a0 + r * 128 + k4 * 4);
#pragma unroll
    for (int kk = 0; kk < 4; ++kk) {
      const float4 w0 = sW[(k4 * 4 + kk) * 32 + tc * 2];
      const float4 w1 = sW[(k4 * 4 + kk) * 32 + tc * 2 + 1];
#pragma unroll
      for (int r = 0; r < 8; ++r) {
        const float av = reinterpret_cast<const float*>(&a[r])[kk];
        fma4(acc0[r], av, w0);
        fma4(acc1[r], av, w1);
      }
    }
  }
  const float4 b0 = reinterpret_cast<const float4*>(bias)[tc * 2];
  const float4 b1 = reinterpret_cast<const float4*>(bias)[tc * 2 + 1];
#pragma unroll
  for (int r = 0; r < 8; ++r) {
    float4 o0 = acc0[r], o1 = acc1[r];
    o0.x += b0.x; o0.y += b0.y; o0.z += b0.z; o0.w += b0.w;
    o1.x += b1.x; o1.y += b1.y; o1.z += b1.z; o1.w += b1.w;
    float4* outp = reinterpret_cast<float4*>(Out + (row0 + r) * 128 + tc * 8);
    outp[0] = o0; outp[1] = o1;
  }
}

// 5 GEMMs in one launch: which = blockIdx.x>>9 (512 blocks each)
__global__ __launch_bounds__(256) void gemm_multi(
    const float* __restrict__ x,
    const float* __restrict__ Wq, const float* __restrict__ bq, float* __restrict__ q,
    const float* __restrict__ Wk, const float* __restrict__ bk, float* __restrict__ kl,
    const float* __restrict__ Wv, const float* __restrict__ bv, float* __restrict__ vl,
    const float* __restrict__ Ws, const float* __restrict__ bs, float* __restrict__ sl,
    const float* __restrict__ Wc, const float* __restrict__ bc, float* __restrict__ qw) {
  const int which = blockIdx.x >> 9;
  const int bid = blockIdx.x & 511;
  if (which == 0)      gemm_body(x, Wq, bq, q,  bid);
  else if (which == 1) gemm_body(x, Wk, bk, kl, bid);
  else if (which == 2) gemm_body(x, Wv, bv, vl, bid);
  else if (which == 3) gemm_body(x, Ws, bs, sl, bid);
  else                 gemm_body(x, Wc, bc, qw, bid);
}

// ====== final GEMM: out = relu(agge@We + be + aggv + sl); outc + score epilogue ======
__global__ __launch_bounds__(256) void gemm_final(
    const float* __restrict__ A, const float* __restrict__ W,
    const float* __restrict__ bias, const float* __restrict__ aggv,
    const float* __restrict__ sl, const float* __restrict__ pwn,
    float* __restrict__ outc, float* __restrict__ score) {
  __shared__ float4 sW[128 * 32];
  const int t = threadIdx.x;
  const float4* W4 = reinterpret_cast<const float4*>(W);
#pragma unroll
  for (int i = 0; i < 16; ++i) sW[t + i * 256] = W4[t + i * 256];
  const int tc = t & 15;
  const int tr = t >> 4;
  const size_t row0 = (size_t)blockIdx.x * 128 + tr * 8;
  const float* a0 = A + row0 * 128;
  float4 acc0[8], acc1[8];
#pragma unroll
  for (int r = 0; r < 8; ++r) {
    acc0[r] = make_float4(0.f, 0.f, 0.f, 0.f);
    acc1[r] = make_float4(0.f, 0.f, 0.f, 0.f);
  }
  __syncthreads();
#pragma unroll 4
  for (int k4 = 0; k4 < 32; ++k4) {
    float4 a[8];
#pragma unroll
    for (int r = 0; r < 8; ++r)
      a[r] = *reinterpret_cast<const float4*>(a0 + r * 128 + k4 * 4);
#pragma unroll
    for (int kk = 0; kk < 4; ++kk) {
      const float4 w0 = sW[(k4 * 4 + kk) * 32 + tc * 2];
      const float4 w1 = sW[(k4 * 4 + kk) * 32 + tc * 2 + 1];
#pragma unroll
      for (int r = 0; r < 8; ++r) {
        const float av = reinterpret_cast<const float*>(&a[r])[kk];
        fma4(acc0[r], av, w0);
        fma4(acc1[r], av, w1);
      }
    }
  }
  const float4 b0 = reinterpret_cast<const float4*>(bias)[tc * 2];
  const float4 b1 = reinterpret_cast<const float4*>(bias)[tc * 2 + 1];
  const float4 p0 = reinterpret_cast<const float4*>(pwn)[tc * 2];
  const float4 p1 = reinterpret_cast<const float4*>(pwn)[tc * 2 + 1];
#pragma unroll
  for (int r = 0; r < 8; ++r) {
    const float4 v0 = reinterpret_cast<const float4*>(aggv + (row0 + r) * 128 + tc * 8)[0];
    const float4 v1 = reinterpret_cast<const float4*>(aggv + (row0 + r) * 128 + tc * 8)[1];
    const float4 s0 = reinterpret_cast<const float4*>(sl + (row0 + r) * 128 + tc * 8)[0];
    const float4 s1 = reinterpret_cast<const float4*>(sl + (row0 + r) * 128 + tc * 8)[1];
    float4 o0, o1;
    o0.x = fmaxf(acc0[r].x + b0.x + v0.x + s0.x, 0.f);
    o0.y = fmaxf(acc0[r].y + b0.y + v0.y + s0.y, 0.f);
    o0.z = fmaxf(acc0[r].z + b0.z + v0.z + s0.z, 0.f);
    o0.w = fmaxf(acc0[r].w + b0.w + v0.w + s0.w, 0.f);
    o1.x = fmaxf(acc1[r].x + b1.x + v1.x + s1.x, 0.f);
    o1.y = fmaxf(acc1[r].y + b1.y + v1.y + s1.y, 0.f);
    o1.z = fmaxf(acc1[r].z + b1.z + v1.z + s1.z, 0.f);
    o1.w = fmaxf(acc1[r].w + b1.w + v1.w + s1.w, 0.f);
    float4* outp = reinterpret_cast<float4*>(outc + (row0 + r) * 128 + tc * 8);
    outp[0] = o0; outp[1] = o1;
    float sp = o0.x * p0.x + o0.y * p0.y + o0.z * p0.z + o0.w * p0.w +
               o1.x * p1.x + o1.y * p1.y + o1.z * p1.z + o1.w * p1.w;
#pragma unroll
    for (int d = 1; d < 16; d <<= 1) sp += __shfl_xor(sp, d, 16);
    if (tc == 0) score[row0 + r] = tanhf(sp);
  }
}

// ============ Wc[t,i] = sum_d Wq[t,d]*We[i,d];  bc[i] = sum_d bq[d]*We[i,d] ============
__global__ void wc_kernel(const float* __restrict__ Wq, const float* __restrict__ bq,
                          const float* __restrict__ We, float* __restrict__ Wc,
                          float* __restrict__ bc) {
  __shared__ float sWe[128];
  const int i = blockIdx.x;    // output col (in-index of We row)
  const int t = threadIdx.x;   // 128 threads = output row
  sWe[t] = We[i * 128 + t];
  __syncthreads();
  float s = 0.f;
  for (int d = 0; d < 128; ++d) s = fmaf(Wq[t * 128 + d], sWe[d], s);
  Wc[t * 128 + i] = s;
  if (t == 0) {
    float sb = 0.f;
    for (int d = 0; d < 128; ++d) sb = fmaf(bq[d], sWe[d], sb);
    bc[i] = sb;
  }
}

// ---------------- init ----------------
__global__ void init_kernel(int* __restrict__ deg, int* __restrict__ nmap,
                            float* __restrict__ bn2) {
  const int i = blockIdx.x * 256 + threadIdx.x;
  if (i < NODES) { deg[i] = 0; nmap[i] = -1; }
  if (i < 256) bn2[i] = 0.f;   // bnsum[128] + bnsq[128] contiguous
}

__global__ void pwn_kernel(const float* __restrict__ pool_w, float* __restrict__ pwn) {
  __shared__ float red[128];
  const int t = threadIdx.x;
  const float vv = pool_w[t];
  red[t] = vv * vv;
  __syncthreads();
  for (int d = 64; d > 0; d >>= 1) {
    if (t < d) red[t] += red[t + d];
    __syncthreads();
  }
  pwn[t] = vv * rsqrtf(red[0]);
}

// ---------------- CSR build ----------------
__global__ void deg_kernel(const int* __restrict__ dst, int* __restrict__ deg) {
  const int e = blockIdx.x * 256 + threadIdx.x;
  atomicAdd(&deg[dst[e]], 1);
}

__global__ __launch_bounds__(1024) void scan_kernel(const int* __restrict__ deg,
                                                    int* __restrict__ offs) {
  __shared__ int part[1024];
  const int t = threadIdx.x;
  const int base = t * 64;
  int s = 0;
  for (int j = 0; j < 64; ++j) s += deg[base + j];
  part[t] = s;
  __syncthreads();
  for (int d = 1; d < 1024; d <<= 1) {
    const int add = (t >= d) ? part[t - d] : 0;
    __syncthreads();
    part[t] += add;
    __syncthreads();
  }
  int run = part[t] - s;
  for (int j = 0; j < 64; ++j) { offs[base + j] = run; run += deg[base + j]; }
  if (t == 1023) offs[NODES] = run;
}

__global__ void copy_int(const int* __restrict__ a, int* __restrict__ b) {
  const int i = blockIdx.x * 256 + threadIdx.x;
  if (i < NODES) b[i] = a[i];
}

__global__ void scatter_kernel(const int* __restrict__ dst, int* __restrict__ woff,
                               int* __restrict__ eid) {
  const int e = blockIdx.x * 256 + threadIdx.x;
  const int pos = atomicAdd(&woff[dst[e]], 1);
  eid[pos] = e;
}

// ========== fused attention: 4x16-lane groups per wave, 2 edges/group in flight ==========
__global__ __launch_bounds__(256) void attn_v3(
    const float* __restrict__ q, const float* __restrict__ k,
    const float* __restrict__ v, const float* __restrict__ qw,
    const float* __restrict__ ea, const float* __restrict__ be,
    const int* __restrict__ srcArr, const int* __restrict__ offs,
    const int* __restrict__ eid, float* __restrict__ aggv,
    float* __restrict__ agge) {
  int b = blockIdx.x;
  b = (b & 7) * 2048 + (b >> 3);                        // XCD-bijective swizzle (16384%8==0)
  const int wid = b * 4 + (threadIdx.x >> 6);
  const int lane = threadIdx.x & 63;
  const int g = lane >> 4;        // edge-group 0..3
  const int l = lane & 15;        // lane within group; owns dims 8l..8l+7
  const float4* q4  = reinterpret_cast<const float4*>(q)  + (size_t)wid * 32;
  const float4* qw4 = reinterpret_cast<const float4*>(qw) + (size_t)wid * 32;
  const float4* be4 = reinterpret_cast<const float4*>(be);
  const float4 qv0 = q4[2 * l],  qv1 = q4[2 * l + 1];
  const float4 qwv0 = qw4[2 * l], qwv1 = qw4[2 * l + 1];
  float qbe = dot4(qv0, be4[2 * l]) + dot4(qv1, be4[2 * l + 1]);
#pragma unroll
  for (int d = 1; d < 16; d <<= 1) qbe += __shfl_xor(qbe, d, 64);

  const float4* k4  = reinterpret_cast<const float4*>(k);
  const float4* v4  = reinterpret_cast<const float4*>(v);
  const float4* ea4 = reinterpret_cast<const float4*>(ea);
  float denom = 0.f;
  float4 av0 = make_float4(0.f, 0.f, 0.f, 0.f), av1 = av0, ae0 = av0, ae1 = av0;
  const int e0 = offs[wid], e1 = offs[wid + 1];
  for (int p = e0 + g; p < e1; p += 8) {
    const bool h2 = (p + 4) < e1;
    const int eA = eid[p];
    const int eB = h2 ? eid[p + 4] : eA;
    const int sA = srcArr[eA];
    const int sB = srcArr[eB];
    const size_t oA = (size_t)sA * 32 + 2 * l, oB = (size_t)sB * 32 + 2 * l;
    const size_t fA = (size_t)eA * 32 + 2 * l, fB = (size_t)eB * 32 + 2 * l;
    const float4 kA0 = k4[oA], kA1 = k4[oA + 1];
    const float4 eA0 = ea4[fA], eA1 = ea4[fA + 1];
    const float4 vA0 = v4[oA], vA1 = v4[oA + 1];
    const float4 kB0 = k4[oB], kB1 = k4[oB + 1];
    const float4 eB0 = ea4[fB], eB1 = ea4[fB + 1];
    const float4 vB0 = v4[oB], vB1 = v4[oB + 1];
    float pA = dot4(qv0, kA0) + dot4(qv1, kA1) + dot4(qwv0, eA0) + dot4(qwv1, eA1);
    float pB = dot4(qv0, kB0) + dot4(qv1, kB1) + dot4(qwv0, eB0) + dot4(qwv1, eB1);
#pragma unroll
    for (int d = 1; d < 16; d <<= 1) {
      pA += __shfl_xor(pA, d, 64);
      pB += __shfl_xor(pB, d, 64);
    }
    const float wA = expf((pA + qbe) * 0.08838834764831845f);
    const float wB = h2 ? expf((pB + qbe) * 0.08838834764831845f) : 0.f;
    denom += wA + wB;
    fma4(av0, wA, vA0); fma4(av1, wA, vA1);
    fma4(ae0, wA, eA0); fma4(ae1, wA, eA1);
    fma4(av0, wB, vB0); fma4(av1, wB, vB1);
    fma4(ae0, wB, eB0); fma4(ae1, wB, eB1);
  }
  // cross-group combine (xor 16, 32)
#pragma unroll
  for (int d = 16; d < 64; d <<= 1) {
    denom += __shfl_xor(denom, d, 64);
    av0.x += __shfl_xor(av0.x, d, 64); av0.y += __shfl_xor(av0.y, d, 64);
    av0.z += __shfl_xor(av0.z, d, 64); av0.w += __shfl_xor(av0.w, d, 64);
    av1.x += __shfl_xor(av1.x, d, 64); av1.y += __shfl_xor(av1.y, d, 64);
    av1.z += __shfl_xor(av1.z, d, 64); av1.w += __shfl_xor(av1.w, d, 64);
    ae0.x += __shfl_xor(ae0.x, d, 64); ae0.y += __shfl_xor(ae0.y, d, 64);
    ae0.z += __shfl_xor(ae0.z, d, 64); ae0.w += __shfl_xor(ae0.w, d, 64);
    ae1.x += __shfl_xor(ae1.x, d, 64); ae1.y += __shfl_xor(ae1.y, d, 64);
    ae1.z += __shfl_xor(ae1.z, d, 64); ae1.w += __shfl_xor(ae1.w, d, 64);
  }
  if (g == 0) {
    const float inv = 1.f / (denom + 1e-16f);
    float4* aggv4 = reinterpret_cast<float4*>(aggv) + (size_t)wid * 32;
    float4* agge4 = reinterpret_cast<float4*>(agge) + (size_t)wid * 32;
    aggv4[2 * l]     = make_float4(av0.x * inv, av0.y * inv, av0.z * inv, av0.w * inv);
    aggv4[2 * l + 1] = make_float4(av1.x * inv, av1.y * inv, av1.z * inv, av1.w * inv);
    agge4[2 * l]     = make_float4(ae0.x * inv, ae0.y * inv, ae0.z * inv, ae0.w * inv);
    agge4[2 * l + 1] = make_float4(ae1.x * inv, ae1.y * inv, ae1.z * inv, ae1.w * inv);
  }
}

// -------- per-graph top-k via bitonic sort (desc, tie -> lower index) --------
__global__ __launch_bounds__(1024) void topk_kernel(
    const float* __restrict__ score, int* __restrict__ perm,
    float* __restrict__ tops, float* __restrict__ batchf) {
  __shared__ float ss[1024];
  __shared__ int si[1024];
  const int b = blockIdx.x, t = threadIdx.x;
  ss[t] = score[b * 1024 + t];
  si[t] = t;
  __syncthreads();
  for (int size = 2; size <= 1024; size <<= 1) {
    for (int stride = size >> 1; stride > 0; stride >>= 1) {
      const int j = t ^ stride;
      if (j > t) {
        const float s1 = ss[t], s2 = ss[j];
        const int i1 = si[t], i2 = si[j];
        const bool bj = (s2 > s1) || (s2 == s1 && i2 < i1);
        const bool dir = ((t & size) == 0);
        if (dir ? bj : !bj) { ss[t] = s2; ss[j] = s1; si[t] = i2; si[j] = i1; }
      }
      __syncthreads();
    }
  }
  if (t < TOPK) {
    const int g = b * TOPK + t;
    perm[g] = b * 1024 + si[t];
    tops[g] = ss[t];
    batchf[g] = (float)b;
  }
}

__global__ void nm_set(const int* __restrict__ perm, int* __restrict__ nm) {
  const int i = blockIdx.x * 256 + threadIdx.x;
  if (i < BKR) nm[perm[i]] = i;
}

// ------------- gather xp = out[perm]*top_s + BN partial sums -------------
__global__ __launch_bounds__(128) void xp_kernel(
    const float* __restrict__ outc, const int* __restrict__ perm,
    const float* __restrict__ tops, float* __restrict__ y,
    float* __restrict__ bnsum, float* __restrict__ bnsq) {
  const int t = threadIdx.x;
  const int r0 = blockIdx.x * 128;
  float s = 0.f, s2 = 0.f;
  for (int i = 0; i < 128; ++i) {
    const int r = r0 + i;
    const int g = perm[r];
    const float val = outc[(size_t)g * DIM + t] * tops[r];
    y[(size_t)r * DIM + t] = val;
    s += val;
    s2 = fmaf(val, val, s2);
  }
  atomicAdd(&bnsum[t], s);
  atomicAdd(&bnsq[t], s2);
}

__global__ void bnfinal_kernel(const float* __restrict__ bnsum, const float* __restrict__ bnsq,
                               const float* __restrict__ gamma, const float* __restrict__ beta,
                               float* __restrict__ bnA, float* __restrict__ bnC) {
  const int t = threadIdx.x;
  const float mu = bnsum[t] * (1.f / BKR);
  const float var = bnsq[t] * (1.f / BKR) - mu * mu;
  const float inv = rsqrtf(var + 1e-5f);
  const float a = gamma[t] * inv;
  bnA[t] = a;
  bnC[t] = beta[t] - mu * a;
}

__global__ __launch_bounds__(256) void bnapply_kernel(float* __restrict__ y,
                                                      const float* __restrict__ bnA,
                                                      const float* __restrict__ bnC) {
  const size_t i4 = (size_t)blockIdx.x * 256 + threadIdx.x;   // BKR*32 float4s
  const int c4 = (int)(i4 & 31);
  const float4 a4 = reinterpret_cast<const float4*>(bnA)[c4];
  const float4 c4v = reinterpret_cast<const float4*>(bnC)[c4];
  float4 v = reinterpret_cast<float4*>(y)[i4];
  v.x = fmaf(v.x, a4.x, c4v.x);
  v.y = fmaf(v.y, a4.y, c4v.y);
  v.z = fmaf(v.z, a4.z, c4v.z);
  v.w = fmaf(v.w, a4.w, c4v.w);
  reinterpret_cast<float4*>(y)[i4] = v;
}

// ---------------- edge remap + valid ----------------
__global__ void efilter_kernel(const int* __restrict__ srcArr, const int* __restrict__ dstArr,
                               const int* __restrict__ nm, float* __restrict__ nei,
                               float* __restrict__ validf) {
  const int e = blockIdx.x * 256 + threadIdx.x;
  const int ns = nm[srcArr[e]];
  const int nd = nm[dstArr[e]];
  const bool val = (ns >= 0) && (nd >= 0);
  nei[e] = val ? (float)ns : -1.f;
  nei[NEDGE + e] = val ? (float)nd : -1.f;
  validf[e] = val ? 1.f : 0.f;
}

// new_edge_attr: skip reading invalid rows (write zeros), 8 rows per 256-thread block
__global__ __launch_bounds__(256) void nea_kernel(const float* __restrict__ ea,
                                                  const float* __restrict__ validf,
                                                  float* __restrict__ nea) {
  const int t = threadIdx.x;
  const int row = blockIdx.x * 8 + (t >> 5);
  const int lane = t & 31;
  const size_t i4 = (size_t)row * 32 + lane;
  float4 v = make_float4(0.f, 0.f, 0.f, 0.f);
  if (validf[row] > 0.5f) v = reinterpret_cast<const float4*>(ea)[i4];
  reinterpret_cast<float4*>(nea)[i4] = v;
}

// ---------------- launch ----------------
extern "C" void kernel_launch(void* const* d_in, const int* in_sizes, int n_in,
                              void* d_out, int out_size, void* d_ws, size_t ws_size,
                              hipStream_t stream) {
  const float* x     = (const float*)d_in[0];
  const int*   eidx  = (const int*)d_in[1];
  const float* eattr = (const float*)d_in[2];
  const float* Wq = (const float*)d_in[4];  const float* bq = (const float*)d_in[5];
  const float* Wk = (const float*)d_in[6];  const float* bk = (const float*)d_in[7];
  const float* Wv = (const float*)d_in[8];  const float* bv = (const float*)d_in[9];
  const float* We = (const float*)d_in[10]; const float* be = (const float*)d_in[11];
  const float* Ws = (const float*)d_in[12]; const float* bs = (const float*)d_in[13];
  const float* pool_w = (const float*)d_in[14];
  const float* gamma  = (const float*)d_in[15];
  const float* beta   = (const float*)d_in[16];

  const int* srcArr = eidx;
  const int* dstArr = eidx + NEDGE;

  float* out = (float*)d_out;
  // output layout (floats)
  float* y      = out;                                   // BKR*128
  float* nei    = out + (size_t)BKR * DIM;               // 2*NEDGE
  float* nea    = nei + 2 * (size_t)NEDGE;               // NEDGE*128
  float* batchf = nea + (size_t)NEDGE * DIM;             // BKR
  float* validf = batchf + BKR;                          // NEDGE

  // big node arrays staged inside the (not-yet-written) nea region: 8 x 32MB = 256MB
  float* q    = nea + 0 * NM;
  float* kl   = nea + 1 * NM;
  float* vl   = nea + 2 * NM;
  float* sl   = nea + 3 * NM;
  float* qw   = nea + 4 * NM;
  float* aggv = nea + 5 * NM;
  float* agge = nea + 6 * NM;
  float* outc = nea + 7 * NM;

  // workspace layout (small)
  char* w = (char*)d_ws;
  size_t off = 0;
  float* score= (float*)(w + off); off += (size_t)NODES * 4;
  float* pwn  = (float*)(w + off); off += 128 * 4;
  float* Wc   = (float*)(w + off); off += 128 * 128 * 4;
  float* bc   = (float*)(w + off); off += 128 * 4;
  float* tops = (float*)(w + off); off += (size_t)BKR * 4;
  float* bnsum= (float*)(w + off); off += 128 * 4;
  float* bnsq = (float*)(w + off); off += 128 * 4;
  float* bnA  = (float*)(w + off); off += 128 * 4;
  float* bnC  = (float*)(w + off); off += 128 * 4;
  int* deg    = (int*)(w + off); off += (size_t)NODES * 4;
  int* offs   = (int*)(w + off); off += ((size_t)NODES + 1) * 4;
  int* woff   = (int*)(w + off); off += (size_t)NODES * 4;
  int* nmap   = (int*)(w + off); off += (size_t)NODES * 4;
  int* perm   = (int*)(w + off); off += (size_t)BKR * 4;
  int* eid    = (int*)(w + off); off += (size_t)NEDGE * 4;

  // init + tiny precomputes
  init_kernel<<<NODES / 256, 256, 0, stream>>>(deg, nmap, bnsum);
  pwn_kernel<<<1, 128, 0, stream>>>(pool_w, pwn);
  wc_kernel<<<128, 128, 0, stream>>>(Wq, bq, We, Wc, bc);

  // node-level linear layers (q, k, v, skip, qW) in one launch
  gemm_multi<<<5 * (NODES / 128), 256, 0, stream>>>(
      x, Wq, bq, q, Wk, bk, kl, Wv, bv, vl, Ws, bs, sl, Wc, bc, qw);

  // CSR by dst
  deg_kernel<<<NEDGE / 256, 256, 0, stream>>>(dstArr, deg);
  scan_kernel<<<1, 1024, 0, stream>>>(deg, offs);
  copy_int<<<NODES / 256, 256, 0, stream>>>(offs, woff);
  scatter_kernel<<<NEDGE / 256, 256, 0, stream>>>(dstArr, woff, eid);

  // fused attention on raw edge_attr
  attn_v3<<<NODES / 4, 256, 0, stream>>>(q, kl, vl, qw, eattr, be, srcArr, offs, eid,
                                         aggv, agge);

  // final conv output + score
  gemm_final<<<NODES / 128, 256, 0, stream>>>(agge, We, be, aggv, sl, pwn, outc, score);

  // top-k pooling
  topk_kernel<<<NB, 1024, 0, stream>>>(score, perm, tops, batchf);
  nm_set<<<BKR / 256, 256, 0, stream>>>(perm, nmap);

  // xp gather + BN (must finish with outc before nea overwrite)
  xp_kernel<<<BKR / 128, 128, 0, stream>>>(outc, perm, tops, y, bnsum, bnsq);
  bnfinal_kernel<<<1, 128, 0, stream>>>(bnsum, bnsq, gamma, beta, bnA, bnC);
  bnapply_kernel<<<(BKR * 32) / 256, 256, 0, stream>>>(y, bnA, bnC);

  // edge remap + masked edge_attr (overwrites staging region last)
  efilter_kernel<<<NEDGE / 256, 256, 0, stream>>>(srcArr, dstArr, nmap, nei, validf);
  nea_kernel<<<NEDGE / 8, 256, 0, stream>>>(eattr, validf, nea);
}

// Round 5
// 735.285 us; speedup vs baseline: 1.6710x; 1.1086x over previous
//
#include <hip/hip_runtime.h>
#include <cstddef>
#include <cstdint>

#define NODES 65536      // B*N
#define NEDGE 1048576    // B*E_PER
#define NB    64
#define NPER  1024
#define TOPK  512
#define BKR   32768      // NB*TOPK
#define DIM   128
#define NM    ((size_t)NODES * DIM)   // floats per node-array

typedef float f32x4 __attribute__((ext_vector_type(4)));

__device__ __forceinline__ f32x4 ntload4(const f32x4* p) {
  return __builtin_nontemporal_load(p);
}
__device__ __forceinline__ void ntstore4(f32x4* p, f32x4 v) {
  __builtin_nontemporal_store(v, p);
}
__device__ __forceinline__ long long ntloadll(const long long* p) {
  return __builtin_nontemporal_load(p);
}
__device__ __forceinline__ float dotv(f32x4 a, f32x4 b) {
  return fmaf(a.x, b.x, fmaf(a.y, b.y, fmaf(a.z, b.z, a.w * b.w)));
}

// ================= shared GEMM core: Out[row0..row0+7] = A-rows @ sW + bias =============
__device__ __forceinline__ void gemm_core(
    const float* __restrict__ A, const f32x4* __restrict__ sW,
    const float* __restrict__ bias, float* __restrict__ Out,
    size_t row0, int ostride, int tc) {
  const float* a0 = A + row0 * 128;
  f32x4 acc0[8], acc1[8];
#pragma unroll
  for (int r = 0; r < 8; ++r) { acc0[r] = (f32x4)(0.f); acc1[r] = (f32x4)(0.f); }
#pragma unroll 4
  for (int k4 = 0; k4 < 32; ++k4) {
    f32x4 a[8];
#pragma unroll
    for (int r = 0; r < 8; ++r)
      a[r] = *reinterpret_cast<const f32x4*>(a0 + r * 128 + k4 * 4);
#pragma unroll
    for (int kk = 0; kk < 4; ++kk) {
      const f32x4 w0 = sW[(k4 * 4 + kk) * 32 + tc * 2];
      const f32x4 w1 = sW[(k4 * 4 + kk) * 32 + tc * 2 + 1];
#pragma unroll
      for (int r = 0; r < 8; ++r) {
        const float av = a[r][kk];
        acc0[r] += av * w0;
        acc1[r] += av * w1;
      }
    }
  }
  const f32x4 b0 = reinterpret_cast<const f32x4*>(bias)[tc * 2];
  const f32x4 b1 = reinterpret_cast<const f32x4*>(bias)[tc * 2 + 1];
#pragma unroll
  for (int r = 0; r < 8; ++r) {
    f32x4* outp = reinterpret_cast<f32x4*>(Out + (row0 + r) * (size_t)ostride + tc * 8);
    outp[0] = acc0[r] + b0;
    outp[1] = acc1[r] + b1;
  }
}

// 5 GEMMs in one launch, 512 threads, 256 rows/block; k,v interleaved into kv[*][256]
__global__ __launch_bounds__(512) void gemm_multi(
    const float* __restrict__ x,
    const float* __restrict__ Wq, const float* __restrict__ bq, float* __restrict__ q,
    const float* __restrict__ Wk, const float* __restrict__ bk,
    const float* __restrict__ Wv, const float* __restrict__ bv, float* __restrict__ kv,
    const float* __restrict__ Ws, const float* __restrict__ bs, float* __restrict__ sl,
    const float* __restrict__ Wc, const float* __restrict__ bc, float* __restrict__ qw) {
  __shared__ f32x4 sW[128 * 32];
  const int which = blockIdx.x >> 8;
  const int bid = blockIdx.x & 255;
  const int t = threadIdx.x;
  const float* W; const float* bias; float* Out; int ostride = 128;
  if (which == 0)      { W = Wq; bias = bq; Out = q; }
  else if (which == 1) { W = Wk; bias = bk; Out = kv;       ostride = 256; }
  else if (which == 2) { W = Wv; bias = bv; Out = kv + 128; ostride = 256; }
  else if (which == 3) { W = Ws; bias = bs; Out = sl; }
  else                 { W = Wc; bias = bc; Out = qw; }
  const f32x4* W4 = reinterpret_cast<const f32x4*>(W);
#pragma unroll
  for (int i = 0; i < 8; ++i) sW[t + i * 512] = W4[t + i * 512];
  __syncthreads();
  gemm_core(x, sW, bias, Out, (size_t)bid * 256 + (t >> 4) * 8, ostride, t & 15);
}

// ====== final GEMM: out = relu(agge@We + be + aggv + sl); outc + score epilogue ======
__global__ __launch_bounds__(256) void gemm_final(
    const float* __restrict__ A, const float* __restrict__ W,
    const float* __restrict__ bias, const float* __restrict__ aggv,
    const float* __restrict__ sl, const float* __restrict__ pwn,
    float* __restrict__ outc, float* __restrict__ score) {
  __shared__ f32x4 sW[128 * 32];
  const int t = threadIdx.x;
  const f32x4* W4 = reinterpret_cast<const f32x4*>(W);
#pragma unroll
  for (int i = 0; i < 16; ++i) sW[t + i * 256] = W4[t + i * 256];
  const int tc = t & 15;
  const size_t row0 = (size_t)blockIdx.x * 128 + (t >> 4) * 8;
  const float* a0 = A + row0 * 128;
  f32x4 acc0[8], acc1[8];
#pragma unroll
  for (int r = 0; r < 8; ++r) { acc0[r] = (f32x4)(0.f); acc1[r] = (f32x4)(0.f); }
  __syncthreads();
#pragma unroll 4
  for (int k4 = 0; k4 < 32; ++k4) {
    f32x4 a[8];
#pragma unroll
    for (int r = 0; r < 8; ++r)
      a[r] = *reinterpret_cast<const f32x4*>(a0 + r * 128 + k4 * 4);
#pragma unroll
    for (int kk = 0; kk < 4; ++kk) {
      const f32x4 w0 = sW[(k4 * 4 + kk) * 32 + tc * 2];
      const f32x4 w1 = sW[(k4 * 4 + kk) * 32 + tc * 2 + 1];
#pragma unroll
      for (int r = 0; r < 8; ++r) {
        const float av = a[r][kk];
        acc0[r] += av * w0;
        acc1[r] += av * w1;
      }
    }
  }
  const f32x4 b0 = reinterpret_cast<const f32x4*>(bias)[tc * 2];
  const f32x4 b1 = reinterpret_cast<const f32x4*>(bias)[tc * 2 + 1];
  const f32x4 p0 = reinterpret_cast<const f32x4*>(pwn)[tc * 2];
  const f32x4 p1 = reinterpret_cast<const f32x4*>(pwn)[tc * 2 + 1];
#pragma unroll
  for (int r = 0; r < 8; ++r) {
    const f32x4 v0 = reinterpret_cast<const f32x4*>(aggv + (row0 + r) * 128 + tc * 8)[0];
    const f32x4 v1 = reinterpret_cast<const f32x4*>(aggv + (row0 + r) * 128 + tc * 8)[1];
    const f32x4 s0 = reinterpret_cast<const f32x4*>(sl + (row0 + r) * 128 + tc * 8)[0];
    const f32x4 s1 = reinterpret_cast<const f32x4*>(sl + (row0 + r) * 128 + tc * 8)[1];
    f32x4 o0 = acc0[r] + b0 + v0 + s0;
    f32x4 o1 = acc1[r] + b1 + v1 + s1;
#pragma unroll
    for (int c = 0; c < 4; ++c) { o0[c] = fmaxf(o0[c], 0.f); o1[c] = fmaxf(o1[c], 0.f); }
    f32x4* outp = reinterpret_cast<f32x4*>(outc + (row0 + r) * 128 + tc * 8);
    outp[0] = o0; outp[1] = o1;
    float sp = dotv(o0, p0) + dotv(o1, p1);
#pragma unroll
    for (int d = 1; d < 16; d <<= 1) sp += __shfl_xor(sp, d, 16);
    if (tc == 0) score[row0 + r] = tanhf(sp);
  }
}

// ============ Wc[t,i] = sum_d Wq[t,d]*We[i,d];  bc[i] = sum_d bq[d]*We[i,d] ============
__global__ void wc_kernel(const float* __restrict__ Wq, const float* __restrict__ bq,
                          const float* __restrict__ We, float* __restrict__ Wc,
                          float* __restrict__ bc) {
  __shared__ float sWe[128];
  const int i = blockIdx.x;
  const int t = threadIdx.x;
  sWe[t] = We[i * 128 + t];
  __syncthreads();
  float s = 0.f;
  for (int d = 0; d < 128; ++d) s = fmaf(Wq[t * 128 + d], sWe[d], s);
  Wc[t * 128 + i] = s;
  if (t == 0) {
    float sb = 0.f;
    for (int d = 0; d < 128; ++d) sb = fmaf(bq[d], sWe[d], sb);
    bc[i] = sb;
  }
}

// ---------------- init ----------------
__global__ void init_kernel(int* __restrict__ deg, int* __restrict__ nmap,
                            float* __restrict__ bn2) {
  const int i = blockIdx.x * 256 + threadIdx.x;
  if (i < NODES) { deg[i] = 0; nmap[i] = -1; }
  if (i < 256) bn2[i] = 0.f;   // bnsum[128] + bnsq[128] contiguous
}

__global__ void pwn_kernel(const float* __restrict__ pool_w, float* __restrict__ pwn) {
  __shared__ float red[128];
  const int t = threadIdx.x;
  const float vv = pool_w[t];
  red[t] = vv * vv;
  __syncthreads();
  for (int d = 64; d > 0; d >>= 1) {
    if (t < d) red[t] += red[t + d];
    __syncthreads();
  }
  pwn[t] = vv * rsqrtf(red[0]);
}

// ---------------- CSR build ----------------
__global__ void deg_kernel(const int* __restrict__ dst, int* __restrict__ deg) {
  const int e = blockIdx.x * 256 + threadIdx.x;
  atomicAdd(&deg[dst[e]], 1);
}

__global__ __launch_bounds__(1024) void scan_kernel(const int* __restrict__ deg,
                                                    int* __restrict__ offs,
                                                    int* __restrict__ woff) {
  __shared__ int part[1024];
  const int t = threadIdx.x;
  const int base = t * 64;
  int s = 0;
  for (int j = 0; j < 64; ++j) s += deg[base + j];
  part[t] = s;
  __syncthreads();
  for (int d = 1; d < 1024; d <<= 1) {
    const int add = (t >= d) ? part[t - d] : 0;
    __syncthreads();
    part[t] += add;
    __syncthreads();
  }
  int run = part[t] - s;
  for (int j = 0; j < 64; ++j) {
    offs[base + j] = run; woff[base + j] = run;
    run += deg[base + j];
  }
  if (t == 1023) offs[NODES] = run;
}

// sorted edge array: packed (src<<32 | e)
__global__ void scatter_kernel(const int* __restrict__ dst, const int* __restrict__ src,
                               int* __restrict__ woff, long long* __restrict__ srt) {
  const int e = blockIdx.x * 256 + threadIdx.x;
  const int pos = atomicAdd(&woff[dst[e]], 1);
  srt[pos] = ((long long)src[e] << 32) | (unsigned)e;
}

// ========== fused attention: 4x16-lane groups per wave, 2 edges/group in flight ==========
// kv interleaved [node][256]; ea read with NONTEMPORAL loads (keep kv/q/qw L2-resident)
__global__ __launch_bounds__(256) void attn_v4(
    const float* __restrict__ q, const float* __restrict__ kv,
    const float* __restrict__ qw, const float* __restrict__ ea,
    const float* __restrict__ be, const long long* __restrict__ srt,
    const int* __restrict__ offs, float* __restrict__ aggv,
    float* __restrict__ agge) {
  int b = blockIdx.x;
  b = (b & 7) * 2048 + (b >> 3);                        // XCD-bijective swizzle (16384%8==0)
  const int wid = b * 4 + (threadIdx.x >> 6);
  const int lane = threadIdx.x & 63;
  const int g = lane >> 4;        // edge-group 0..3
  const int l = lane & 15;        // lane within group; owns dims 8l..8l+7
  const f32x4* q4  = reinterpret_cast<const f32x4*>(q)  + (size_t)wid * 32;
  const f32x4* qw4 = reinterpret_cast<const f32x4*>(qw) + (size_t)wid * 32;
  const f32x4* be4 = reinterpret_cast<const f32x4*>(be);
  const f32x4 qv0 = q4[2 * l],  qv1 = q4[2 * l + 1];
  const f32x4 qwv0 = qw4[2 * l], qwv1 = qw4[2 * l + 1];
  float qbe = dotv(qv0, be4[2 * l]) + dotv(qv1, be4[2 * l + 1]);
#pragma unroll
  for (int d = 1; d < 16; d <<= 1) qbe += __shfl_xor(qbe, d, 64);

  const f32x4* kv4 = reinterpret_cast<const f32x4*>(kv);
  const f32x4* ea4 = reinterpret_cast<const f32x4*>(ea);
  float denom = 0.f;
  f32x4 av0 = (f32x4)(0.f), av1 = (f32x4)(0.f), ag0 = (f32x4)(0.f), ag1 = (f32x4)(0.f);
  const int e0 = offs[wid], e1 = offs[wid + 1];
  for (int p = e0 + g; p < e1; p += 8) {
    const bool h2 = (p + 4) < e1;
    const long long pkA = ntloadll(srt + p);
    const long long pkB = h2 ? ntloadll(srt + p + 4) : pkA;
    const int eA = (int)pkA, sA = (int)(pkA >> 32);
    const int eB = (int)pkB, sB = (int)(pkB >> 32);
    const f32x4* kvA = kv4 + (size_t)sA * 64 + 2 * l;
    const f32x4* kvB = kv4 + (size_t)sB * 64 + 2 * l;
    const f32x4 kA0 = kvA[0], kA1 = kvA[1], vA0 = kvA[32], vA1 = kvA[33];
    const f32x4 kB0 = kvB[0], kB1 = kvB[1], vB0 = kvB[32], vB1 = kvB[33];
    const f32x4 fA0 = ntload4(ea4 + (size_t)eA * 32 + 2 * l);
    const f32x4 fA1 = ntload4(ea4 + (size_t)eA * 32 + 2 * l + 1);
    const f32x4 fB0 = ntload4(ea4 + (size_t)eB * 32 + 2 * l);
    const f32x4 fB1 = ntload4(ea4 + (size_t)eB * 32 + 2 * l + 1);
    float pA = dotv(qv0, kA0) + dotv(qv1, kA1) + dotv(qwv0, fA0) + dotv(qwv1, fA1);
    float pB = dotv(qv0, kB0) + dotv(qv1, kB1) + dotv(qwv0, fB0) + dotv(qwv1, fB1);
#pragma unroll
    for (int d = 1; d < 16; d <<= 1) {
      pA += __shfl_xor(pA, d, 64);
      pB += __shfl_xor(pB, d, 64);
    }
    const float wA = expf((pA + qbe) * 0.08838834764831845f);   // /sqrt(128)
    const float wB = h2 ? expf((pB + qbe) * 0.08838834764831845f) : 0.f;
    denom += wA + wB;
    av0 += wA * vA0 + wB * vB0;
    av1 += wA * vA1 + wB * vB1;
    ag0 += wA * fA0 + wB * fB0;
    ag1 += wA * fA1 + wB * fB1;
  }
  // cross-group combine (xor 16, 32)
#pragma unroll
  for (int d = 16; d < 64; d <<= 1) {
    denom += __shfl_xor(denom, d, 64);
#pragma unroll
    for (int c = 0; c < 4; ++c) {
      av0[c] += __shfl_xor(av0[c], d, 64);
      av1[c] += __shfl_xor(av1[c], d, 64);
      ag0[c] += __shfl_xor(ag0[c], d, 64);
      ag1[c] += __shfl_xor(ag1[c], d, 64);
    }
  }
  if (g == 0) {
    const float inv = 1.f / (denom + 1e-16f);
    f32x4* aggv4 = reinterpret_cast<f32x4*>(aggv) + (size_t)wid * 32;
    f32x4* agge4 = reinterpret_cast<f32x4*>(agge) + (size_t)wid * 32;
    aggv4[2 * l]     = av0 * inv;
    aggv4[2 * l + 1] = av1 * inv;
    agge4[2 * l]     = ag0 * inv;
    agge4[2 * l + 1] = ag1 * inv;
  }
}

// -------- per-graph top-k via bitonic sort (desc, tie -> lower index); writes nmap --------
__global__ __launch_bounds__(1024) void topk_kernel(
    const float* __restrict__ score, int* __restrict__ perm,
    float* __restrict__ tops, float* __restrict__ batchf, int* __restrict__ nmap) {
  __shared__ float ss[1024];
  __shared__ int si[1024];
  const int b = blockIdx.x, t = threadIdx.x;
  ss[t] = score[b * 1024 + t];
  si[t] = t;
  __syncthreads();
  for (int size = 2; size <= 1024; size <<= 1) {
    for (int stride = size >> 1; stride > 0; stride >>= 1) {
      const int j = t ^ stride;
      if (j > t) {
        const float s1 = ss[t], s2 = ss[j];
        const int i1 = si[t], i2 = si[j];
        const bool bj = (s2 > s1) || (s2 == s1 && i2 < i1);
        const bool dir = ((t & size) == 0);
        if (dir ? bj : !bj) { ss[t] = s2; ss[j] = s1; si[t] = i2; si[j] = i1; }
      }
      __syncthreads();
    }
  }
  if (t < TOPK) {
    const int g = b * TOPK + t;
    perm[g] = b * 1024 + si[t];
    tops[g] = ss[t];
    batchf[g] = (float)b;
    nmap[b * 1024 + si[t]] = g;
  }
}

// ------------- gather xp = out[perm]*top_s + BN partial sums -------------
__global__ __launch_bounds__(128) void xp_kernel(
    const float* __restrict__ outc, const int* __restrict__ perm,
    const float* __restrict__ tops, float* __restrict__ y,
    float* __restrict__ bnsum, float* __restrict__ bnsq) {
  const int t = threadIdx.x;
  const int r0 = blockIdx.x * 128;
  float s = 0.f, s2 = 0.f;
  for (int i = 0; i < 128; ++i) {
    const int r = r0 + i;
    const int g = perm[r];
    const float val = outc[(size_t)g * DIM + t] * tops[r];
    y[(size_t)r * DIM + t] = val;
    s += val;
    s2 = fmaf(val, val, s2);
  }
  atomicAdd(&bnsum[t], s);
  atomicAdd(&bnsq[t], s2);
}

// BN finalize folded into apply: each thread derives a/c for its 4 columns
__global__ __launch_bounds__(256) void bnapply_v2(
    float* __restrict__ y, const float* __restrict__ bnsum, const float* __restrict__ bnsq,
    const float* __restrict__ gamma, const float* __restrict__ beta) {
  const size_t i4 = (size_t)blockIdx.x * 256 + threadIdx.x;   // BKR*32 float4s
  const int c4 = (int)(i4 & 31);
  f32x4 a, c;
#pragma unroll
  for (int j = 0; j < 4; ++j) {
    const int col = c4 * 4 + j;
    const float mu = bnsum[col] * (1.f / BKR);
    const float var = bnsq[col] * (1.f / BKR) - mu * mu;
    const float aa = gamma[col] * rsqrtf(var + 1e-5f);
    a[j] = aa;
    c[j] = beta[col] - mu * aa;
  }
  f32x4 v = reinterpret_cast<f32x4*>(y)[i4];
#pragma unroll
  for (int j = 0; j < 4; ++j) v[j] = fmaf(v[j], a[j], c[j]);
  reinterpret_cast<f32x4*>(y)[i4] = v;
}

// ---------------- fused edge remap + valid + masked edge_attr ----------------
__global__ __launch_bounds__(256) void efnea_kernel(
    const int* __restrict__ srcArr, const int* __restrict__ dstArr,
    const int* __restrict__ nm, const float* __restrict__ ea,
    float* __restrict__ nei, float* __restrict__ validf, float* __restrict__ nea) {
  const int row = blockIdx.x * 8 + (threadIdx.x >> 5);
  const int lane = threadIdx.x & 31;
  const int ns = nm[srcArr[row]];
  const int nd = nm[dstArr[row]];
  const bool val = (ns >= 0) && (nd >= 0);
  if (lane == 0) {
    nei[row] = val ? (float)ns : -1.f;
    nei[NEDGE + row] = val ? (float)nd : -1.f;
    validf[row] = val ? 1.f : 0.f;
  }
  const size_t i4 = (size_t)row * 32 + lane;
  f32x4 v = (f32x4)(0.f);
  if (val) v = ntload4(reinterpret_cast<const f32x4*>(ea) + i4);
  ntstore4(reinterpret_cast<f32x4*>(nea) + i4, v);
}

// ---------------- launch ----------------
extern "C" void kernel_launch(void* const* d_in, const int* in_sizes, int n_in,
                              void* d_out, int out_size, void* d_ws, size_t ws_size,
                              hipStream_t stream) {
  const float* x     = (const float*)d_in[0];
  const int*   eidx  = (const int*)d_in[1];
  const float* eattr = (const float*)d_in[2];
  const float* Wq = (const float*)d_in[4];  const float* bq = (const float*)d_in[5];
  const float* Wk = (const float*)d_in[6];  const float* bk = (const float*)d_in[7];
  const float* Wv = (const float*)d_in[8];  const float* bv = (const float*)d_in[9];
  const float* We = (const float*)d_in[10]; const float* be = (const float*)d_in[11];
  const float* Ws = (const float*)d_in[12]; const float* bs = (const float*)d_in[13];
  const float* pool_w = (const float*)d_in[14];
  const float* gamma  = (const float*)d_in[15];
  const float* beta   = (const float*)d_in[16];

  const int* srcArr = eidx;
  const int* dstArr = eidx + NEDGE;

  float* out = (float*)d_out;
  // output layout (floats)
  float* y      = out;                                   // BKR*128
  float* nei    = out + (size_t)BKR * DIM;               // 2*NEDGE
  float* nea    = nei + 2 * (size_t)NEDGE;               // NEDGE*128
  float* batchf = nea + (size_t)NEDGE * DIM;             // BKR
  float* validf = batchf + BKR;                          // NEDGE

  // big node arrays staged inside the (not-yet-written) nea region: 8 x NM = 256MB
  float* q    = nea + 0 * NM;
  float* kv   = nea + 1 * NM;   // 2*NM (k|v interleaved, 256 floats/row)
  float* sl   = nea + 3 * NM;
  float* qw   = nea + 4 * NM;
  float* aggv = nea + 5 * NM;
  float* agge = nea + 6 * NM;
  float* outc = nea + 7 * NM;

  // workspace layout (small)
  char* w = (char*)d_ws;
  size_t off = 0;
  float* score= (float*)(w + off); off += (size_t)NODES * 4;
  float* pwn  = (float*)(w + off); off += 128 * 4;
  float* Wc   = (float*)(w + off); off += 128 * 128 * 4;
  float* bc   = (float*)(w + off); off += 128 * 4;
  float* tops = (float*)(w + off); off += (size_t)BKR * 4;
  float* bnsum= (float*)(w + off); off += 128 * 4;
  float* bnsq = (float*)(w + off); off += 128 * 4;
  int* deg    = (int*)(w + off); off += (size_t)NODES * 4;
  int* offs   = (int*)(w + off); off += ((size_t)NODES + 8) * 4;
  int* woff   = (int*)(w + off); off += (size_t)NODES * 4;
  int* nmap   = (int*)(w + off); off += (size_t)NODES * 4;
  int* perm   = (int*)(w + off); off += (size_t)BKR * 4;
  long long* srt = (long long*)(w + off); off += (size_t)NEDGE * 8;

  // init + tiny precomputes
  init_kernel<<<NODES / 256, 256, 0, stream>>>(deg, nmap, bnsum);
  pwn_kernel<<<1, 128, 0, stream>>>(pool_w, pwn);
  wc_kernel<<<128, 128, 0, stream>>>(Wq, bq, We, Wc, bc);

  // node-level linear layers (q, k|v, skip, qW) in one launch
  gemm_multi<<<5 * 256, 512, 0, stream>>>(
      x, Wq, bq, q, Wk, bk, Wv, bv, kv, Ws, bs, sl, Wc, bc, qw);

  // CSR by dst
  deg_kernel<<<NEDGE / 256, 256, 0, stream>>>(dstArr, deg);
  scan_kernel<<<1, 1024, 0, stream>>>(deg, offs, woff);
  scatter_kernel<<<NEDGE / 256, 256, 0, stream>>>(dstArr, srcArr, woff, srt);

  // fused attention on raw edge_attr (NT stream)
  attn_v4<<<NODES / 4, 256, 0, stream>>>(q, kv, qw, eattr, be, srt, offs, aggv, agge);

  // final conv output + score
  gemm_final<<<NODES / 128, 256, 0, stream>>>(agge, We, be, aggv, sl, pwn, outc, score);

  // top-k pooling (writes perm/tops/batch + nmap)
  topk_kernel<<<NB, 1024, 0, stream>>>(score, perm, tops, batchf, nmap);

  // xp gather + BN (must finish with outc before nea overwrite)
  xp_kernel<<<BKR / 128, 128, 0, stream>>>(outc, perm, tops, y, bnsum, bnsq);
  bnapply_v2<<<(BKR * 32) / 256, 256, 0, stream>>>(y, bnsum, bnsq, gamma, beta);

  // fused edge remap + masked edge_attr (overwrites staging region last)
  efnea_kernel<<<NEDGE / 8, 256, 0, stream>>>(srcArr, dstArr, nmap, eattr, nei, validf, nea);
}